// Round 7
// baseline (579.855 us; speedup 1.0000x reference)
//
#include <hip/hip_runtime.h>

#define HW    4096
#define CKD   64
#define CVD   512
#define NBATCH 8
#define BQ    64       // q per block
#define BCV   256      // cv rows per block (cv-split in 2 groups)
#define BM    64
#define NIT   64       // HW / BM
#define PSTR  72       // P-tile LDS row stride (bf16 elems): 144 B rows, 16B-aligned

typedef __attribute__((ext_vector_type(8))) short  short8;
typedef __attribute__((ext_vector_type(4))) float  floatx4;
typedef __attribute__((ext_vector_type(4))) int    intx4;
typedef __attribute__((ext_vector_type(2))) int    intx2;
typedef __attribute__((ext_vector_type(2))) float  floatx2;

static __device__ __forceinline__ unsigned short f2bf(float f) {
  unsigned u = __float_as_uint(f);
  u = (u + 0x7fffu + ((u >> 16) & 1u)) >> 16;   // RTNE
  return (unsigned short)u;
}
static __device__ __forceinline__ unsigned pack2(float a, float b) {
  return (unsigned)f2bf(a) | ((unsigned)f2bf(b) << 16);
}

// ---------------- merged pre-pass ----------------
// bx <128: Mk transpose+convert; 128..255: Qk; >=256: Mv pairwise convert.
__global__ __launch_bounds__(256) void prepass(
    const float* __restrict__ Mk, const float* __restrict__ Qk,
    const float* __restrict__ Mv,
    unsigned short* __restrict__ mkw, unsigned short* __restrict__ qkw,
    unsigned short* __restrict__ mvw)
{
  const int bx = blockIdx.x;
  if (bx < 256) {
    const float* src = (bx < 128) ? Mk : Qk;
    unsigned short* dstp = (bx < 128) ? mkw : qkw;
    const int bb = (bx & 127) >> 4;                       // batch
    const int m  = ((bx & 15) << 8) | threadIdx.x;
    const float* s = src + (size_t)bb * CKD * HW + m;
    intx4* d = (intx4*)(dstp + ((size_t)bb * HW + m) * CKD);
    #pragma unroll
    for (int v = 0; v < 8; ++v) {
      intx4 o;
      #pragma unroll
      for (int k = 0; k < 4; ++k) {
        float f0 = s[(size_t)(v * 8 + 2 * k    ) * HW];
        float f1 = s[(size_t)(v * 8 + 2 * k + 1) * HW];
        o[k] = (int)pack2(f0, f1);
      }
      d[v] = o;
    }
  } else {
    const size_t i = (size_t)(bx - 256) * 256 + threadIdx.x;
    const floatx4* s = (const floatx4*)Mv + i * 2;
    floatx4 f0 = s[0], f1 = s[1];
    intx4 o;
    o[0] = (int)pack2(f0.x, f0.y);
    o[1] = (int)pack2(f0.z, f0.w);
    o[2] = (int)pack2(f1.x, f1.y);
    o[3] = (int)pack2(f1.z, f1.w);
    ((intx4*)mvw)[i] = o;
  }
}

// fragment loaders, templated on storage dtype (BF=true: bf16 in ws)
template<bool BF>
static __device__ __forceinline__ short8 ld8_strided(const char* p, int idx) {
  short8 f;
  if constexpr (BF) {
    const unsigned short* q = (const unsigned short*)p + idx;
    #pragma unroll
    for (int j = 0; j < 8; ++j) f[j] = (short)q[(size_t)j * HW];
  } else {
    const float* q = (const float*)p + idx;
    #pragma unroll
    for (int j = 0; j < 8; ++j) f[j] = (short)f2bf(q[(size_t)j * HW]);
  }
  return f;
}
template<bool BF>
static __device__ __forceinline__ short8 ld8_contig(const char* p, size_t idx) {
  if constexpr (BF) {
    union { intx4 i; short8 s; } u;
    u.i = *(const intx4*)((const unsigned short*)p + idx);
    return u.s;
  } else {
    const float* q = (const float*)p + idx;
    short8 f;
    #pragma unroll
    for (int j = 0; j < 4; ++j) {
      unsigned v = pack2(q[2*j], q[2*j+1]);
      f[2*j]   = (short)(v & 0xffffu);
      f[2*j+1] = (short)(v >> 16);
    }
    return f;
  }
}

// A-fragment of mk (BF: from mkT [HW][CK], one dwordx4)
template<bool BF>
static __device__ __forceinline__ short8 ldA(const char* mk, int m0, int mh,
                                             int ks, int quad, int col) {
  if constexpr (BF)
    return ld8_contig<true>(mk, (size_t)(m0 + mh*16 + col) * CKD + ks*32 + quad*8);
  else
    return ld8_strided<false>(mk, (ks*32 + quad*8) * HW + m0 + mh*16 + col);
}

#define MFMA16(a, b, c) __builtin_amdgcn_mfma_f32_16x16x32_bf16((a), (b), (c), 0, 0, 0)

// BF=true:  mk = mkT [HW][CK] bf16, qk = qkT [HW][CK] bf16, mv = [CV][HW] bf16
// BF=false: original f32 layouts ([CK][HW], [CK][HW], [CV][HW])
//
// 256 threads (4 waves), block owns BQ=64 q-cols x BCV=256 cv rows (cv-split
// in 2 groups). Wave w: GEMM1 q-tile w; GEMM2 cv rows [cvb + w*64, +64).
// acc[4][4]=64 regs + ~100 arch -> launch_bounds(256,3): 3 waves/SIMD
// (12 waves/CU, vs 8 before). GEMM1 duplicated across the 2 cv-groups
// (accepted: +1/8 MFMA, +exp) to buy +50% occupancy.
template<bool BF>
__global__ __launch_bounds__(256, 3) void attn_main(
    const void* __restrict__ Mkp, const void* __restrict__ Qkp,
    const void* __restrict__ Mvp, float* __restrict__ Out)
{
  __shared__ alignas(16) short Pt[2][BQ * PSTR];   // 18432 B
  __shared__ float lsum[BQ];

  const int bx   = blockIdx.x;
  const int b    = bx & 7;            // XCD-affine: batch b -> XCD b
  const int q0   = ((bx >> 3) & 63) * BQ;
  const int cvb  = (bx >> 9) * BCV;   // cv-group base (0 or 256)
  const int tid  = threadIdx.x;
  const int w    = tid >> 6;          // wave 0..3
  const int lane = tid & 63;
  const int quad = lane >> 4;
  const int col  = lane & 15;

  const size_t esz = BF ? 2 : 4;
  const char* mk = (const char*)Mkp + (size_t)b * CKD * HW * esz;
  const char* qk = (const char*)Qkp + (size_t)b * CKD * HW * esz;
  const char* mv = (const char*)Mvp + (size_t)b * CVD * HW * esz;
  float*      out = Out + (size_t)b * CVD * HW;

  if (tid < BQ) lsum[tid] = 0.0f;

  // B-fragments of qk (fixed for whole block): wave w owns q-tile w.
  short8 bq[2];
  #pragma unroll
  for (int ks = 0; ks < 2; ++ks) {
    if constexpr (BF)
      bq[ks] = ld8_contig<true>(qk, (size_t)(q0 + w*16 + col) * CKD + ks*32 + quad*8);
    else
      bq[ks] = ld8_strided<false>(qk, (ks*32 + quad*8) * HW + q0 + w*16 + col);
  }

  floatx4 acc[4][4];   // [ch][qh]: wave w owns cv rows [cvb+w*64, +64), 64 q
  #pragma unroll
  for (int i = 0; i < 4; ++i)
    #pragma unroll
    for (int j = 0; j < 4; ++j) acc[i][j] = (floatx4)0.0f;

  float lacc = 0.0f;
  const float SC = 0.18033688011112042f;   // (1/sqrt(64)) * log2(e)

  __syncthreads();

  for (int it = 0; it < NIT; ++it) {
    const int m0 = it * BM;
    short* Pb = &Pt[it & 1][0];

    // ---- prefetch mv fragments for GEMM2: issued before GEMM1 so L2 latency
    //      hides under GEMM1 compute (consumed only after the barrier)
    short8 av[4][2];
    #pragma unroll
    for (int ch = 0; ch < 4; ++ch)
      #pragma unroll
      for (int ks = 0; ks < 2; ++ks)
        av[ch][ks] = ld8_contig<BF>(mv,
            (size_t)(cvb + w*64 + ch*16 + col) * HW + m0 + ks*32 + quad*8);

    // ---- GEMM1: S[m][q], wave w does tiles (mh=0..3, q-tile w); exp -> P^T
    #pragma unroll
    for (int mh = 0; mh < 4; ++mh) {
      floatx4 s = (floatx4)0.0f;
      #pragma unroll
      for (int ks = 0; ks < 2; ++ks)
        s = MFMA16(ldA<BF>(mk, m0, mh, ks, quad, col), bq[ks], s);
      // C layout: n=q=col, m = quad*4 + r
      const float p0 = exp2f(s[0] * SC);
      const float p1 = exp2f(s[1] * SC);
      const float p2 = exp2f(s[2] * SC);
      const float p3 = exp2f(s[3] * SC);
      lacc += (p0 + p1) + (p2 + p3);
      intx2 pv;
      pv[0] = (int)pack2(p0, p1);
      pv[1] = (int)pack2(p2, p3);
      *(intx2*)(Pb + (w*16 + col) * PSTR + mh*16 + quad*4) = pv;
    }
    __syncthreads();   // single barrier/iter; P double-buffered

    // ---- GEMM2: O[cv][q] += mv[cv][m] * P[m][q]
    #pragma unroll
    for (int qh = 0; qh < 4; ++qh) {
      union { intx4 i; short8 s; } u0, u1;
      u0.i = *(const intx4*)(Pb + (qh*16 + col) * PSTR + quad*8);
      u1.i = *(const intx4*)(Pb + (qh*16 + col) * PSTR + 32 + quad*8);
      #pragma unroll
      for (int ch = 0; ch < 4; ++ch) {
        acc[ch][qh] = MFMA16(av[ch][0], u0.s, acc[ch][qh]);
        acc[ch][qh] = MFMA16(av[ch][1], u1.s, acc[ch][qh]);
      }
    }
  }

  // ---- softmax denominators: 4 quads contribute per q column
  atomicAdd(&lsum[w*16 + col], lacc);
  __syncthreads();

  float rl[4];
  #pragma unroll
  for (int qh = 0; qh < 4; ++qh) rl[qh] = 1.0f / lsum[qh*16 + col];

  // ---- epilogue: normalize + store f32
  #pragma unroll
  for (int ch = 0; ch < 4; ++ch) {
    #pragma unroll
    for (int r = 0; r < 4; ++r) {
      const int cv = cvb + w*64 + ch*16 + quad*4 + r;
      float* orow = out + (size_t)cv * HW + q0 + col;
      #pragma unroll
      for (int qh = 0; qh < 4; ++qh)
        orow[qh*16] = acc[ch][qh][r] * rl[qh];
    }
  }
}

extern "C" void kernel_launch(void* const* d_in, const int* in_sizes, int n_in,
                              void* d_out, int out_size, void* d_ws, size_t ws_size,
                              hipStream_t stream) {
  const float* Mk = (const float*)d_in[0];
  const float* Qk = (const float*)d_in[1];
  const float* Mv = (const float*)d_in[2];
  float* Out = (float*)d_out;
  (void)in_sizes; (void)n_in; (void)out_size;

  const size_t NMK = (size_t)NBATCH * CKD * HW;   // 2,097,152
  const size_t NMV = (size_t)NBATCH * CVD * HW;   // 16,777,216
  const size_t need = (2 * NMK + NMV) * 2;        // 41,943,040 B

  const int grid = NBATCH * (HW / BQ) * (CVD / BCV);   // 8*64*2 = 1024

  if (ws_size >= need) {
    unsigned short* mkw = (unsigned short*)d_ws;
    unsigned short* qkw = mkw + NMK;
    unsigned short* mvw = qkw + NMK;
    const int mvBlocks = (int)(NMV / (256 * 8));  // 8 elems/thread
    prepass<<<256 + mvBlocks, 256, 0, stream>>>(Mk, Qk, Mv, mkw, qkw, mvw);
    attn_main<true><<<grid, 256, 0, stream>>>(mkw, qkw, mvw, Out);
  } else {
    attn_main<false><<<grid, 256, 0, stream>>>(Mk, Qk, Mv, Out);
  }
}

// Round 8
// 309.694 us; speedup vs baseline: 1.8723x; 1.8723x over previous
//
#include <hip/hip_runtime.h>

#define HW    4096
#define CKD   64
#define CVD   512
#define NBATCH 8
#define BQ    128
#define BMS   512      // m-chunk per super-iteration
#define NSIT  8        // HW / BMS
#define PSTR  72       // P-tile LDS row stride (bf16 elems): 144 B rows, 16B-aligned
#define TILE_SH (BQ * PSTR)   // shorts per 64-m P tile: 9216 (18432 B)

typedef __attribute__((ext_vector_type(8))) short  short8;
typedef __attribute__((ext_vector_type(4))) float  floatx4;
typedef __attribute__((ext_vector_type(4))) int    intx4;
typedef __attribute__((ext_vector_type(2))) int    intx2;
typedef __attribute__((ext_vector_type(2))) float  floatx2;

static __device__ __forceinline__ unsigned short f2bf(float f) {
  unsigned u = __float_as_uint(f);
  u = (u + 0x7fffu + ((u >> 16) & 1u)) >> 16;   // RTNE
  return (unsigned short)u;
}
static __device__ __forceinline__ unsigned pack2(float a, float b) {
  return (unsigned)f2bf(a) | ((unsigned)f2bf(b) << 16);
}
// packed f32->bf16 RTNE, single instruction (T12 recipe)
static __device__ __forceinline__ int cvtpk(float a, float b) {
  int r;
  asm("v_cvt_pk_bf16_f32 %0, %1, %2" : "=v"(r) : "v"(a), "v"(b));
  return r;
}

// ---------------- merged pre-pass ----------------
// bx <128: Mk transpose+convert; 128..255: Qk; >=256: Mv pairwise convert.
__global__ __launch_bounds__(256) void prepass(
    const float* __restrict__ Mk, const float* __restrict__ Qk,
    const float* __restrict__ Mv,
    unsigned short* __restrict__ mkw, unsigned short* __restrict__ qkw,
    unsigned short* __restrict__ mvw)
{
  const int bx = blockIdx.x;
  if (bx < 256) {
    const float* src = (bx < 128) ? Mk : Qk;
    unsigned short* dstp = (bx < 128) ? mkw : qkw;
    const int bb = (bx & 127) >> 4;                       // batch
    const int m  = ((bx & 15) << 8) | threadIdx.x;
    const float* s = src + (size_t)bb * CKD * HW + m;
    intx4* d = (intx4*)(dstp + ((size_t)bb * HW + m) * CKD);
    #pragma unroll
    for (int v = 0; v < 8; ++v) {
      intx4 o;
      #pragma unroll
      for (int k = 0; k < 4; ++k) {
        float f0 = s[(size_t)(v * 8 + 2 * k    ) * HW];
        float f1 = s[(size_t)(v * 8 + 2 * k + 1) * HW];
        o[k] = (int)pack2(f0, f1);
      }
      d[v] = o;
    }
  } else {
    const size_t i = (size_t)(bx - 256) * 256 + threadIdx.x;
    const floatx4* s = (const floatx4*)Mv + i * 2;
    floatx4 f0 = s[0], f1 = s[1];
    intx4 o;
    o[0] = (int)pack2(f0.x, f0.y);
    o[1] = (int)pack2(f0.z, f0.w);
    o[2] = (int)pack2(f1.x, f1.y);
    o[3] = (int)pack2(f1.z, f1.w);
    ((intx4*)mvw)[i] = o;
  }
}

// fragment loaders, templated on storage dtype (BF=true: bf16 in ws)
template<bool BF>
static __device__ __forceinline__ short8 ld8_strided(const char* p, int idx) {
  short8 f;
  if constexpr (BF) {
    const unsigned short* q = (const unsigned short*)p + idx;
    #pragma unroll
    for (int j = 0; j < 8; ++j) f[j] = (short)q[(size_t)j * HW];
  } else {
    const float* q = (const float*)p + idx;
    #pragma unroll
    for (int j = 0; j < 8; ++j) f[j] = (short)f2bf(q[(size_t)j * HW]);
  }
  return f;
}
template<bool BF>
static __device__ __forceinline__ short8 ld8_contig(const char* p, size_t idx) {
  if constexpr (BF) {
    union { intx4 i; short8 s; } u;
    u.i = *(const intx4*)((const unsigned short*)p + idx);
    return u.s;
  } else {
    const float* q = (const float*)p + idx;
    short8 f;
    #pragma unroll
    for (int j = 0; j < 4; ++j) {
      unsigned v = pack2(q[2*j], q[2*j+1]);
      f[2*j]   = (short)(v & 0xffffu);
      f[2*j+1] = (short)(v >> 16);
    }
    return f;
  }
}

// mk fragment at absolute m-row (BF: mkT [HW][CK], one dwordx4)
template<bool BF>
static __device__ __forceinline__ short8 ld_mk(const char* mk, int m, int ks,
                                               int quad, int col) {
  if constexpr (BF)
    return ld8_contig<true>(mk, (size_t)(m + col) * CKD + ks*32 + quad*8);
  else
    return ld8_strided<false>(mk, (ks*32 + quad*8) * HW + m + col);
}

#define MFMA16(a, b, c) __builtin_amdgcn_mfma_f32_16x16x32_bf16((a), (b), (c), 0, 0, 0)

// BF=true:  mk = mkT [HW][CK] bf16, qk = qkT [HW][CK] bf16, mv = [CV][HW] bf16
// BF=false: original f32 layouts ([CK][HW], [CK][HW], [CV][HW])
//
// 512 threads (8 waves), 256 blocks (1/CU). Super-iteration over m-chunks of
// BMS=512 (8 P tiles of 64m x 128q in 147 KB LDS, single-buffered):
//   G1: wave (qh2=w>>2, mq=w&3) computes S[mq*128..+128)[qh2*64..+64)
//       (m-split: mk read duplication 8x -> 2x), exp -> P tiles
//   barrier
//   G2: wave w: cv rows [w*64,+64) x all 128 q over 512 m = 512 MFMA
//   barrier (before next G1 overwrites P)
// Barriers: 64 -> 15; per-iteration latencies amortized 8x.
template<bool BF>
__global__ __launch_bounds__(512, 2) void attn_main(
    const void* __restrict__ Mkp, const void* __restrict__ Qkp,
    const void* __restrict__ Mvp, float* __restrict__ Out)
{
  __shared__ alignas(16) short Pt[NSIT * TILE_SH];   // 147456 B
  __shared__ float lsum[BQ];

  const int bx   = blockIdx.x;
  const int b    = bx & 7;            // XCD-affine: batch b -> XCD b
  const int q0   = (bx >> 3) * BQ;
  const int tid  = threadIdx.x;
  const int w    = tid >> 6;          // wave 0..7
  const int lane = tid & 63;
  const int quad = lane >> 4;
  const int col  = lane & 15;
  const int qh2  = w >> 2;            // G1 q-half (0..1)
  const int mq   = w & 3;             // G1 m-quarter (0..3)

  const size_t esz = BF ? 2 : 4;
  const char* mk = (const char*)Mkp + (size_t)b * CKD * HW * esz;
  const char* qk = (const char*)Qkp + (size_t)b * CKD * HW * esz;
  const char* mv = (const char*)Mvp + (size_t)b * CVD * HW * esz;
  float*      out = Out + (size_t)b * CVD * HW;

  if (tid < BQ) lsum[tid] = 0.0f;

  // B-fragments of qk for G1: wave needs its q-half's 4 tiles.
  short8 bq[4][2];
  #pragma unroll
  for (int qt = 0; qt < 4; ++qt)
    #pragma unroll
    for (int ks = 0; ks < 2; ++ks) {
      const int qi = q0 + qh2*64 + qt*16;
      if constexpr (BF)
        bq[qt][ks] = ld8_contig<true>(qk, (size_t)(qi + col) * CKD + ks*32 + quad*8);
      else
        bq[qt][ks] = ld8_strided<false>(qk, (ks*32 + quad*8) * HW + qi + col);
    }

  floatx4 acc[4][8];   // [ch][qh]: wave w owns cv rows [w*64, +64), all 128 q
  #pragma unroll
  for (int i = 0; i < 4; ++i)
    #pragma unroll
    for (int j = 0; j < 8; ++j) acc[i][j] = (floatx4)0.0f;

  float lacc[4] = {0.0f, 0.0f, 0.0f, 0.0f};
  const float SC = 0.18033688011112042f;   // (1/sqrt(64)) * log2(e)

  for (int sit = 0; sit < NSIT; ++sit) {
    const int m0 = sit * BMS;
    if (sit) __syncthreads();        // previous G2 finished reading P

    // ---- G1: S over this wave's 128m x 64q patch; exp -> P^T tiles
    #pragma unroll 2
    for (int mloc = 0; mloc < 8; ++mloc) {
      const int mm = m0 + mq*128 + mloc*16;         // global m of 16-m tile
      const int t  = mq*2 + (mloc >> 2);            // P tile index (0..7)
      const int mc = (mloc & 3) * 16;               // within-tile m offset
      short8 a0 = ld_mk<BF>(mk, mm, 0, quad, col);
      short8 a1 = ld_mk<BF>(mk, mm, 1, quad, col);
      #pragma unroll
      for (int qt = 0; qt < 4; ++qt) {
        floatx4 s = (floatx4)0.0f;
        s = MFMA16(a0, bq[qt][0], s);
        s = MFMA16(a1, bq[qt][1], s);
        // C layout: n=q=col, m = quad*4 + r
        const float p0 = exp2f(s[0] * SC);
        const float p1 = exp2f(s[1] * SC);
        const float p2 = exp2f(s[2] * SC);
        const float p3 = exp2f(s[3] * SC);
        lacc[qt] += (p0 + p1) + (p2 + p3);
        intx2 pv;
        pv[0] = cvtpk(p0, p1);
        pv[1] = cvtpk(p2, p3);
        *(intx2*)(Pt + t*TILE_SH + (qh2*64 + qt*16 + col) * PSTR + mc + quad*4) = pv;
      }
    }
    __syncthreads();                 // P chunk ready

    // ---- G2: O[cv][q] += mv[cv][m] * P[m][q], 512 MFMA/wave uninterrupted
    #pragma unroll 2
    for (int s = 0; s < 16; ++s) {
      short8 av[4];
      #pragma unroll
      for (int ch = 0; ch < 4; ++ch)
        av[ch] = ld8_contig<BF>(mv,
            (size_t)(w*64 + ch*16 + col) * HW + m0 + s*32 + quad*8);
      const short* Pb = Pt + (s >> 1)*TILE_SH + (s & 1)*32 + quad*8;
      #pragma unroll
      for (int qh = 0; qh < 8; ++qh) {
        union { intx4 i; short8 v; } u;
        u.i = *(const intx4*)(Pb + (qh*16 + col) * PSTR);
        #pragma unroll
        for (int ch = 0; ch < 4; ++ch)
          acc[ch][qh] = MFMA16(av[ch], u.v, acc[ch][qh]);
      }
    }
  }

  // ---- softmax denominators
  #pragma unroll
  for (int qt = 0; qt < 4; ++qt)
    atomicAdd(&lsum[qh2*64 + qt*16 + col], lacc[qt]);
  __syncthreads();

  float rl[8];
  #pragma unroll
  for (int qh = 0; qh < 8; ++qh) rl[qh] = 1.0f / lsum[qh*16 + col];

  // ---- epilogue: normalize + store f32
  #pragma unroll
  for (int ch = 0; ch < 4; ++ch) {
    #pragma unroll
    for (int r = 0; r < 4; ++r) {
      const int cv = w*64 + ch*16 + quad*4 + r;
      float* orow = out + (size_t)cv * HW + q0 + col;
      #pragma unroll
      for (int qh = 0; qh < 8; ++qh)
        orow[qh*16] = acc[ch][qh][r] * rl[qh];
    }
  }
}

extern "C" void kernel_launch(void* const* d_in, const int* in_sizes, int n_in,
                              void* d_out, int out_size, void* d_ws, size_t ws_size,
                              hipStream_t stream) {
  const float* Mk = (const float*)d_in[0];
  const float* Qk = (const float*)d_in[1];
  const float* Mv = (const float*)d_in[2];
  float* Out = (float*)d_out;
  (void)in_sizes; (void)n_in; (void)out_size;

  const size_t NMK = (size_t)NBATCH * CKD * HW;   // 2,097,152
  const size_t NMV = (size_t)NBATCH * CVD * HW;   // 16,777,216
  const size_t need = (2 * NMK + NMV) * 2;        // 41,943,040 B

  if (ws_size >= need) {
    unsigned short* mkw = (unsigned short*)d_ws;
    unsigned short* qkw = mkw + NMK;
    unsigned short* mvw = qkw + NMK;
    const int mvBlocks = (int)(NMV / (256 * 8));  // 8 elems/thread
    prepass<<<256 + mvBlocks, 256, 0, stream>>>(Mk, Qk, Mv, mkw, qkw, mvw);
    attn_main<true><<<NBATCH * (HW/BQ), 512, 0, stream>>>(mkw, qkw, mvw, Out);
  } else {
    attn_main<false><<<NBATCH * (HW/BQ), 512, 0, stream>>>(Mk, Qk, Mv, Out);
  }
}

// Round 9
// 306.237 us; speedup vs baseline: 1.8935x; 1.0113x over previous
//
#include <hip/hip_runtime.h>

#define HW    4096
#define CKD   64
#define CVD   512
#define NBATCH 8
#define BQ    128
#define BMS   512      // m-chunk per super-iteration
#define NSIT  8        // HW / BMS
#define PSTR  72       // P-tile LDS row stride (bf16 elems): 144 B rows, 16B-aligned
#define TILE_SH (BQ * PSTR)   // shorts per 64-m P tile: 9216 (18432 B)

typedef __attribute__((ext_vector_type(8))) short  short8;
typedef __attribute__((ext_vector_type(4))) float  floatx4;
typedef __attribute__((ext_vector_type(4))) int    intx4;
typedef __attribute__((ext_vector_type(2))) int    intx2;
typedef __attribute__((ext_vector_type(2))) float  floatx2;

static __device__ __forceinline__ unsigned short f2bf(float f) {
  unsigned u = __float_as_uint(f);
  u = (u + 0x7fffu + ((u >> 16) & 1u)) >> 16;   // RTNE
  return (unsigned short)u;
}
static __device__ __forceinline__ unsigned pack2(float a, float b) {
  return (unsigned)f2bf(a) | ((unsigned)f2bf(b) << 16);
}
// packed f32->bf16 RTNE, single instruction (T12 recipe)
static __device__ __forceinline__ int cvtpk(float a, float b) {
  int r;
  asm("v_cvt_pk_bf16_f32 %0, %1, %2" : "=v"(r) : "v"(a), "v"(b));
  return r;
}

// ---------------- merged pre-pass ----------------
// bx <128: Mk transpose+convert; 128..255: Qk; >=256: Mv pairwise convert.
__global__ __launch_bounds__(256) void prepass(
    const float* __restrict__ Mk, const float* __restrict__ Qk,
    const float* __restrict__ Mv,
    unsigned short* __restrict__ mkw, unsigned short* __restrict__ qkw,
    unsigned short* __restrict__ mvw)
{
  const int bx = blockIdx.x;
  if (bx < 256) {
    const float* src = (bx < 128) ? Mk : Qk;
    unsigned short* dstp = (bx < 128) ? mkw : qkw;
    const int bb = (bx & 127) >> 4;                       // batch
    const int m  = ((bx & 15) << 8) | threadIdx.x;
    const float* s = src + (size_t)bb * CKD * HW + m;
    intx4* d = (intx4*)(dstp + ((size_t)bb * HW + m) * CKD);
    #pragma unroll
    for (int v = 0; v < 8; ++v) {
      intx4 o;
      #pragma unroll
      for (int k = 0; k < 4; ++k) {
        float f0 = s[(size_t)(v * 8 + 2 * k    ) * HW];
        float f1 = s[(size_t)(v * 8 + 2 * k + 1) * HW];
        o[k] = (int)pack2(f0, f1);
      }
      d[v] = o;
    }
  } else {
    const size_t i = (size_t)(bx - 256) * 256 + threadIdx.x;
    const floatx4* s = (const floatx4*)Mv + i * 2;
    floatx4 f0 = s[0], f1 = s[1];
    intx4 o;
    o[0] = (int)pack2(f0.x, f0.y);
    o[1] = (int)pack2(f0.z, f0.w);
    o[2] = (int)pack2(f1.x, f1.y);
    o[3] = (int)pack2(f1.z, f1.w);
    ((intx4*)mvw)[i] = o;
  }
}

// fragment loaders, templated on storage dtype (BF=true: bf16 in ws)
template<bool BF>
static __device__ __forceinline__ short8 ld8_strided(const char* p, int idx) {
  short8 f;
  if constexpr (BF) {
    const unsigned short* q = (const unsigned short*)p + idx;
    #pragma unroll
    for (int j = 0; j < 8; ++j) f[j] = (short)q[(size_t)j * HW];
  } else {
    const float* q = (const float*)p + idx;
    #pragma unroll
    for (int j = 0; j < 8; ++j) f[j] = (short)f2bf(q[(size_t)j * HW]);
  }
  return f;
}
template<bool BF>
static __device__ __forceinline__ short8 ld8_contig(const char* p, size_t idx) {
  if constexpr (BF) {
    union { intx4 i; short8 s; } u;
    u.i = *(const intx4*)((const unsigned short*)p + idx);
    return u.s;
  } else {
    const float* q = (const float*)p + idx;
    short8 f;
    #pragma unroll
    for (int j = 0; j < 4; ++j) {
      unsigned v = pack2(q[2*j], q[2*j+1]);
      f[2*j]   = (short)(v & 0xffffu);
      f[2*j+1] = (short)(v >> 16);
    }
    return f;
  }
}

// mk fragment at absolute m-row (BF: mkT [HW][CK], one dwordx4)
template<bool BF>
static __device__ __forceinline__ short8 ld_mk(const char* mk, int m, int ks,
                                               int quad, int col) {
  if constexpr (BF)
    return ld8_contig<true>(mk, (size_t)(m + col) * CKD + ks*32 + quad*8);
  else
    return ld8_strided<false>(mk, (ks*32 + quad*8) * HW + m + col);
}

#define MFMA16(a, b, c) __builtin_amdgcn_mfma_f32_16x16x32_bf16((a), (b), (c), 0, 0, 0)

// One G2 s-body: 32 MFMA with avUse; prefetch mv for s=SLOAD into avLoad;
// 2-deep rolling P-fragment prefetch in u01 (u01[j] holds P(S, qh) for the
// next qh with qh&1==j; exits holding P(S+1, 0/1), clamped at S=15).
template<bool BF>
static __device__ __forceinline__ void g2_body(
    const char* mv, const short* PtBase, floatx4 (&acc)[4][8],
    short8 (&avUse)[4], short8 (&avLoad)[4], intx4 (&u01)[2],
    int w, int quad, int col, int m0, int S, int SLOAD)
{
  if (SLOAD < 16) {
    #pragma unroll
    for (int ch = 0; ch < 4; ++ch)
      avLoad[ch] = ld8_contig<BF>(mv,
          (size_t)(w*64 + ch*16 + col) * HW + m0 + SLOAD*32 + quad*8);
  }
  const short* Pb = PtBase + (S >> 1)*TILE_SH + (S & 1)*32 + quad*8;
  const int sn = (S < 15) ? S + 1 : 15;
  const short* Pn = PtBase + (sn >> 1)*TILE_SH + (sn & 1)*32 + quad*8;
  #pragma unroll
  for (int qh = 0; qh < 8; ++qh) {
    intx4 un;
    if (qh < 6)
      un = *(const intx4*)(Pb + ((qh + 2)*16 + col) * PSTR);
    else
      un = *(const intx4*)(Pn + ((qh - 6)*16 + col) * PSTR);
    union { intx4 i; short8 v; } cc;
    cc.i = u01[qh & 1];
    #pragma unroll
    for (int ch = 0; ch < 4; ++ch)
      acc[ch][qh] = MFMA16(avUse[ch], cc.v, acc[ch][qh]);
    u01[qh & 1] = un;
  }
}

// BF=true:  mk = mkT [HW][CK] bf16, qk = qkT [HW][CK] bf16, mv = [CV][HW] bf16
// BF=false: original f32 layouts ([CK][HW], [CK][HW], [CV][HW])
//
// 512 threads (8 waves), 256 blocks (1/CU). Super-iteration over m-chunks of
// BMS=512 (8 P tiles of 64m x 128q in 147 KB LDS, single-buffered):
//   G1: wave (qh2=w>>2, mq=w&3) computes S[mq*128..+128)[qh2*64..+64), exp->P
//   barrier
//   G2: wave w: cv rows [w*64,+64) x all 128 q over 512 m = 512 MFMA,
//       with 2-deep LDS-fragment prefetch + 1-body-ahead mv prefetch
//   barrier
template<bool BF>
__global__ __launch_bounds__(512, 2) void attn_main(
    const void* __restrict__ Mkp, const void* __restrict__ Qkp,
    const void* __restrict__ Mvp, float* __restrict__ Out)
{
  __shared__ alignas(16) short Pt[NSIT * TILE_SH];   // 147456 B
  __shared__ float lsum[BQ];

  const int bx   = blockIdx.x;
  const int b    = bx & 7;            // XCD-affine: batch b -> XCD b
  const int q0   = (bx >> 3) * BQ;
  const int tid  = threadIdx.x;
  const int w    = tid >> 6;          // wave 0..7
  const int lane = tid & 63;
  const int quad = lane >> 4;
  const int col  = lane & 15;
  const int qh2  = w >> 2;            // G1 q-half (0..1)
  const int mq   = w & 3;             // G1 m-quarter (0..3)

  const size_t esz = BF ? 2 : 4;
  const char* mk = (const char*)Mkp + (size_t)b * CKD * HW * esz;
  const char* qk = (const char*)Qkp + (size_t)b * CKD * HW * esz;
  const char* mv = (const char*)Mvp + (size_t)b * CVD * HW * esz;
  float*      out = Out + (size_t)b * CVD * HW;

  if (tid < BQ) lsum[tid] = 0.0f;

  // B-fragments of qk for G1: wave needs its q-half's 4 tiles.
  short8 bq[4][2];
  #pragma unroll
  for (int qt = 0; qt < 4; ++qt)
    #pragma unroll
    for (int ks = 0; ks < 2; ++ks) {
      const int qi = q0 + qh2*64 + qt*16;
      if constexpr (BF)
        bq[qt][ks] = ld8_contig<true>(qk, (size_t)(qi + col) * CKD + ks*32 + quad*8);
      else
        bq[qt][ks] = ld8_strided<false>(qk, (ks*32 + quad*8) * HW + qi + col);
    }

  floatx4 acc[4][8];   // [ch][qh]: wave w owns cv rows [w*64, +64), all 128 q
  #pragma unroll
  for (int i = 0; i < 4; ++i)
    #pragma unroll
    for (int j = 0; j < 8; ++j) acc[i][j] = (floatx4)0.0f;

  float lacc[4] = {0.0f, 0.0f, 0.0f, 0.0f};
  const float SC = 0.18033688011112042f;   // (1/sqrt(64)) * log2(e)

  short8 avA[4], avB[4];
  intx4  u01[2];

  for (int sit = 0; sit < NSIT; ++sit) {
    const int m0 = sit * BMS;

    // mv prefetch for this sit's s=0: issued before the barrier + G1 so L2
    // latency resolves under them (previous G2 is done with avA by now)
    #pragma unroll
    for (int ch = 0; ch < 4; ++ch)
      avA[ch] = ld8_contig<BF>(mv,
          (size_t)(w*64 + ch*16 + col) * HW + m0 + quad*8);

    if (sit) __syncthreads();        // previous G2 finished reading P

    // ---- G1: S over this wave's 128m x 64q patch; exp -> P^T tiles
    #pragma unroll 2
    for (int mloc = 0; mloc < 8; ++mloc) {
      const int mm = m0 + mq*128 + mloc*16;         // global m of 16-m tile
      const int t  = mq*2 + (mloc >> 2);            // P tile index (0..7)
      const int mc = (mloc & 3) * 16;               // within-tile m offset
      short8 a0 = ld_mk<BF>(mk, mm, 0, quad, col);
      short8 a1 = ld_mk<BF>(mk, mm, 1, quad, col);
      #pragma unroll
      for (int qt = 0; qt < 4; ++qt) {
        floatx4 s = (floatx4)0.0f;
        s = MFMA16(a0, bq[qt][0], s);
        s = MFMA16(a1, bq[qt][1], s);
        // C layout: n=q=col, m = quad*4 + r
        const float p0 = exp2f(s[0] * SC);
        const float p1 = exp2f(s[1] * SC);
        const float p2 = exp2f(s[2] * SC);
        const float p3 = exp2f(s[3] * SC);
        lacc[qt] += (p0 + p1) + (p2 + p3);
        intx2 pv;
        pv[0] = cvtpk(p0, p1);
        pv[1] = cvtpk(p2, p3);
        *(intx2*)(Pt + t*TILE_SH + (qh2*64 + qt*16 + col) * PSTR + mc + quad*4) = pv;
      }
    }
    __syncthreads();                 // P chunk ready

    // ---- G2: O[cv][q] += mv[cv][m] * P[m][q], pipelined
    // preload P fragments for s=0, qh=0,1
    u01[0] = *(const intx4*)(Pt + quad*8 + (     col) * PSTR);
    u01[1] = *(const intx4*)(Pt + quad*8 + (16 + col) * PSTR);
    #pragma unroll 1
    for (int s2 = 0; s2 < 8; ++s2) {
      const int S = s2 * 2;
      g2_body<BF>(mv, Pt, acc, avA, avB, u01, w, quad, col, m0, S,     S + 1);
      g2_body<BF>(mv, Pt, acc, avB, avA, u01, w, quad, col, m0, S + 1, S + 2);
    }
  }

  // ---- softmax denominators
  #pragma unroll
  for (int qt = 0; qt < 4; ++qt)
    atomicAdd(&lsum[qh2*64 + qt*16 + col], lacc[qt]);
  __syncthreads();

  float rl[8];
  #pragma unroll
  for (int qh = 0; qh < 8; ++qh) rl[qh] = 1.0f / lsum[qh*16 + col];

  // ---- epilogue: normalize + store f32
  #pragma unroll
  for (int ch = 0; ch < 4; ++ch) {
    #pragma unroll
    for (int r = 0; r < 4; ++r) {
      const int cv = w*64 + ch*16 + quad*4 + r;
      float* orow = out + (size_t)cv * HW + q0 + col;
      #pragma unroll
      for (int qh = 0; qh < 8; ++qh)
        orow[qh*16] = acc[ch][qh][r] * rl[qh];
    }
  }
}

extern "C" void kernel_launch(void* const* d_in, const int* in_sizes, int n_in,
                              void* d_out, int out_size, void* d_ws, size_t ws_size,
                              hipStream_t stream) {
  const float* Mk = (const float*)d_in[0];
  const float* Qk = (const float*)d_in[1];
  const float* Mv = (const float*)d_in[2];
  float* Out = (float*)d_out;
  (void)in_sizes; (void)n_in; (void)out_size;

  const size_t NMK = (size_t)NBATCH * CKD * HW;   // 2,097,152
  const size_t NMV = (size_t)NBATCH * CVD * HW;   // 16,777,216
  const size_t need = (2 * NMK + NMV) * 2;        // 41,943,040 B

  if (ws_size >= need) {
    unsigned short* mkw = (unsigned short*)d_ws;
    unsigned short* qkw = mkw + NMK;
    unsigned short* mvw = qkw + NMK;
    const int mvBlocks = (int)(NMV / (256 * 8));  // 8 elems/thread
    prepass<<<256 + mvBlocks, 256, 0, stream>>>(Mk, Qk, Mv, mkw, qkw, mvw);
    attn_main<true><<<NBATCH * (HW/BQ), 512, 0, stream>>>(mkw, qkw, mvw, Out);
  } else {
    attn_main<false><<<NBATCH * (HW/BQ), 512, 0, stream>>>(Mk, Qk, Mv, Out);
  }
}